// Round 1
// baseline (417.330 us; speedup 1.0000x reference)
//
#include <hip/hip_runtime.h>
#include <math.h>

#define B_   8
#define H_   16
#define BH_  (B_*H_)
#define LK_  4096
#define D_   128

#define KTILE 128
#define PADLD 136           // LDS row stride in floats (16B-aligned rows)
#define SEG   8
#define KSEG  (LK_/SEG)     // 512 keys per score/context block

// ---------------- fast tanh (f32, ~1e-6 abs err) ----------------
__device__ __forceinline__ float fast_tanh(float x) {
    float ax = fabsf(x);
    float e  = __expf(2.0f * ax);
    float r  = 1.0f - __fdividef(2.0f, e + 1.0f);
    return copysignf(r, x);
}

// ---------------- kernel 1: tq[bh][e] = Q[bh]·W_q[:,e] ----------------
__global__ void tq_kernel(const float* __restrict__ Q,
                          const float* __restrict__ Wq,
                          float* __restrict__ tq) {
    int bh = blockIdx.x;
    int e  = threadIdx.x;
    const float* q = Q + bh * D_;
    float acc = 0.0f;
#pragma unroll 8
    for (int d = 0; d < D_; ++d)
        acc = fmaf(q[d], Wq[d * D_ + e], acc);
    tq[bh * D_ + e] = acc;
}

// ---------------- kernel 2: pre = K@W_pre + b_pre ; energy ----------------
// grid: (LK/KTILE, BH), block: 256
// Writes pre tile to d_out pre-region, energy (pre-mask) to d_out score-region.
__launch_bounds__(256, 2)
__global__ void main_kernel(const float* __restrict__ K,
                            const float* __restrict__ Wpre,
                            const float* __restrict__ bpre,
                            const float* __restrict__ Wv,
                            const float* __restrict__ tqg,
                            float* __restrict__ pre_out,
                            float* __restrict__ energy_out) {
    __shared__ float lK[KTILE * PADLD];

    const int chunk = blockIdx.x;        // 0..31
    const int bh    = blockIdx.y;        // 0..127
    const int k0    = chunk * KTILE;
    const int t     = threadIdx.x;

    const float* Kbase = K + ((size_t)bh * LK_ + k0) * D_;

    // ---- stage K tile into LDS, float4-swizzled: col4' = col4 ^ (ty_of_row & 7)
#pragma unroll
    for (int i = 0; i < 16; ++i) {
        int f   = i * 256 + t;           // float4 id 0..4095
        int row = f >> 5;                // 0..127
        int c4  = f & 31;                // float4 within row
        float4 v = *(const float4*)(Kbase + (size_t)row * D_ + (c4 << 2));
        int c4s = c4 ^ ((row >> 3) & 7);
        *(float4*)(&lK[row * PADLD + (c4s << 2)]) = v;
    }
    __syncthreads();

    const int tx = t & 15;               // e-group: columns tx*4..+3 and +64
    const int ty = t >> 4;               // k-group: rows ty*8..ty*8+7
    const int e0 = tx << 2;

    float4 acc0[8], acc1[8];
#pragma unroll
    for (int j = 0; j < 8; ++j) {
        acc0[j] = make_float4(0.f, 0.f, 0.f, 0.f);
        acc1[j] = make_float4(0.f, 0.f, 0.f, 0.f);
    }

    const float* lKr = &lK[(ty << 3) * PADLD];
    const int swz = ty & 7;

#pragma unroll 2
    for (int d4 = 0; d4 < 32; ++d4) {
        const int col = ((d4 ^ swz) << 2);
        float4 kq[8];
#pragma unroll
        for (int j = 0; j < 8; ++j)
            kq[j] = *(const float4*)(&lKr[j * PADLD + col]);

        const float* wrow = Wpre + (size_t)(d4 << 2) * D_;
#pragma unroll
        for (int dd = 0; dd < 4; ++dd) {
            const float4 w0 = *(const float4*)(wrow + dd * D_ + e0);
            const float4 w1 = *(const float4*)(wrow + dd * D_ + e0 + 64);
#pragma unroll
            for (int j = 0; j < 8; ++j) {
                const float kv = (dd == 0) ? kq[j].x : (dd == 1) ? kq[j].y
                               : (dd == 2) ? kq[j].z : kq[j].w;
                acc0[j].x = fmaf(kv, w0.x, acc0[j].x);
                acc0[j].y = fmaf(kv, w0.y, acc0[j].y);
                acc0[j].z = fmaf(kv, w0.z, acc0[j].z);
                acc0[j].w = fmaf(kv, w0.w, acc0[j].w);
                acc1[j].x = fmaf(kv, w1.x, acc1[j].x);
                acc1[j].y = fmaf(kv, w1.y, acc1[j].y);
                acc1[j].z = fmaf(kv, w1.z, acc1[j].z);
                acc1[j].w = fmaf(kv, w1.w, acc1[j].w);
            }
        }
    }

    // ---- epilogue: +b_pre -> store pre ; tanh(pre+tq)·W_v -> energy
    const float4 bp0 = *(const float4*)(bpre + e0);
    const float4 bp1 = *(const float4*)(bpre + e0 + 64);
    const float4 tq0 = *(const float4*)(tqg + bh * D_ + e0);
    const float4 tq1 = *(const float4*)(tqg + bh * D_ + e0 + 64);
    const float4 wv0 = *(const float4*)(Wv + e0);
    const float4 wv1 = *(const float4*)(Wv + e0 + 64);

    float ep[8];
    const size_t prebase = ((size_t)bh * LK_ + (size_t)(k0 + (ty << 3))) * D_;
#pragma unroll
    for (int j = 0; j < 8; ++j) {
        float4 r0, r1;
        r0.x = acc0[j].x + bp0.x;  r0.y = acc0[j].y + bp0.y;
        r0.z = acc0[j].z + bp0.z;  r0.w = acc0[j].w + bp0.w;
        r1.x = acc1[j].x + bp1.x;  r1.y = acc1[j].y + bp1.y;
        r1.z = acc1[j].z + bp1.z;  r1.w = acc1[j].w + bp1.w;
        *(float4*)(pre_out + prebase + (size_t)j * D_ + e0)      = r0;
        *(float4*)(pre_out + prebase + (size_t)j * D_ + e0 + 64) = r1;
        float s = 0.0f;
        s = fmaf(fast_tanh(r0.x + tq0.x), wv0.x, s);
        s = fmaf(fast_tanh(r0.y + tq0.y), wv0.y, s);
        s = fmaf(fast_tanh(r0.z + tq0.z), wv0.z, s);
        s = fmaf(fast_tanh(r0.w + tq0.w), wv0.w, s);
        s = fmaf(fast_tanh(r1.x + tq1.x), wv1.x, s);
        s = fmaf(fast_tanh(r1.y + tq1.y), wv1.y, s);
        s = fmaf(fast_tanh(r1.z + tq1.z), wv1.z, s);
        s = fmaf(fast_tanh(r1.w + tq1.w), wv1.w, s);
        ep[j] = s;
    }
    // reduce energy partials across the 16 tx lanes (same wave, 16-aligned groups)
#pragma unroll
    for (int j = 0; j < 8; ++j) {
        float v = ep[j];
        v += __shfl_xor(v, 1, 64);
        v += __shfl_xor(v, 2, 64);
        v += __shfl_xor(v, 4, 64);
        v += __shfl_xor(v, 8, 64);
        ep[j] = v;
    }
    if (tx == 0) {
        const int krow = k0 + (ty << 3);
#pragma unroll
        for (int j = 0; j < 8; ++j)
            energy_out[(size_t)bh * LK_ + krow + j] = ep[j];
    }
}

// ---------------- kernel 3a: per-(b,h) masked max & sum(exp) ----------------
__global__ void ml_kernel(const float* __restrict__ energy,
                          const int* __restrict__ mask,
                          float* __restrict__ ml) {
    const int bh = blockIdx.x;
    const int t  = threadIdx.x;
    const float* e = energy + (size_t)bh * LK_;
    const int*   m = mask   + (size_t)bh * LK_;

    float mx = -1e30f;
    for (int k = t; k < LK_; k += 256) {
        float v = m[k] ? -1.0e6f : e[k];
        mx = fmaxf(mx, v);
    }
#pragma unroll
    for (int off = 32; off > 0; off >>= 1)
        mx = fmaxf(mx, __shfl_xor(mx, off, 64));
    __shared__ float wmax[4];
    if ((t & 63) == 0) wmax[t >> 6] = mx;
    __syncthreads();
    mx = fmaxf(fmaxf(wmax[0], wmax[1]), fmaxf(wmax[2], wmax[3]));

    float sum = 0.0f;
    for (int k = t; k < LK_; k += 256) {
        float v = m[k] ? -1.0e6f : e[k];
        sum += __expf(v - mx);
    }
#pragma unroll
    for (int off = 32; off > 0; off >>= 1)
        sum += __shfl_xor(sum, off, 64);
    __shared__ float wsum[4];
    if ((t & 63) == 0) wsum[t >> 6] = sum;
    __syncthreads();
    if (t == 0) {
        ml[bh * 2]     = mx;
        ml[bh * 2 + 1] = wsum[0] + wsum[1] + wsum[2] + wsum[3];
    }
}

// ---------------- kernel 3b: score + partial context ----------------
// grid: (SEG, BH), block 256. Reads energy from score region, overwrites with score.
__global__ void score_ctx_kernel(const float* __restrict__ energy,
                                 const int* __restrict__ mask,
                                 const float* __restrict__ V,
                                 const float* __restrict__ ml,
                                 float* __restrict__ score_out,
                                 float* __restrict__ part) {
    const int seg = blockIdx.x;
    const int bh  = blockIdx.y;
    const int t   = threadIdx.x;
    const int k0  = seg * KSEG;

    __shared__ float sc[KSEG];
    const float mx  = ml[bh * 2];
    const float inv = 1.0f / ml[bh * 2 + 1];

    for (int kk = t; kk < KSEG; kk += 256) {
        const size_t gi = (size_t)bh * LK_ + k0 + kk;
        float v = mask[gi] ? -1.0e6f : energy[gi];
        float s = __expf(v - mx) * inv;
        sc[kk] = s;
        score_out[gi] = s;
    }
    __syncthreads();

    const int d    = t & 127;
    const int half = t >> 7;
    const float* Vb = V + ((size_t)bh * LK_ + k0) * D_ + d;
    float acc = 0.0f;
    for (int kk = half; kk < KSEG; kk += 2)
        acc = fmaf(sc[kk], Vb[(size_t)kk * D_], acc);

    __shared__ float pl[2][128];
    pl[half][d] = acc;
    __syncthreads();
    if (t < 128)
        part[((size_t)bh * SEG + seg) * D_ + t] = pl[0][t] + pl[1][t];
}

// ---------------- kernel 3c: combine partial contexts ----------------
__global__ void combine_kernel(const float* __restrict__ part,
                               float* __restrict__ ctx) {
    const int bh = blockIdx.x;
    const int d  = threadIdx.x;
    float s = 0.0f;
#pragma unroll
    for (int g = 0; g < SEG; ++g)
        s += part[((size_t)bh * SEG + g) * D_ + d];
    ctx[bh * D_ + d] = s;
}

// ---------------- launch ----------------
extern "C" void kernel_launch(void* const* d_in, const int* in_sizes, int n_in,
                              void* d_out, int out_size, void* d_ws, size_t ws_size,
                              hipStream_t stream) {
    const float* Q    = (const float*)d_in[0];
    const float* K    = (const float*)d_in[1];
    const float* V    = (const float*)d_in[2];
    const int*   mask = (const int*)  d_in[3];
    // d_in[4] = scale (unused by reference)
    const float* Wpre = (const float*)d_in[5];
    const float* bpre = (const float*)d_in[6];
    const float* Wq   = (const float*)d_in[7];
    const float* Wv   = (const float*)d_in[8];

    float* out   = (float*)d_out;
    float* ctx   = out;                           // [BH][D]
    float* score = out + (size_t)BH_ * D_;        // [BH][LK]
    float* pre   = score + (size_t)BH_ * LK_;     // [BH][LK][D]

    float* w    = (float*)d_ws;
    float* tq   = w;                              // BH*D
    float* ml   = tq + (size_t)BH_ * D_;          // BH*2
    float* part = ml + 2 * BH_;                   // BH*SEG*D

    hipLaunchKernelGGL(tq_kernel, dim3(BH_), dim3(D_), 0, stream, Q, Wq, tq);
    hipLaunchKernelGGL(main_kernel, dim3(LK_ / KTILE, BH_), dim3(256), 0, stream,
                       K, Wpre, bpre, Wv, tq, pre, score);
    hipLaunchKernelGGL(ml_kernel, dim3(BH_), dim3(256), 0, stream, score, mask, ml);
    hipLaunchKernelGGL(score_ctx_kernel, dim3(SEG, BH_), dim3(256), 0, stream,
                       score, mask, V, ml, score, part);
    hipLaunchKernelGGL(combine_kernel, dim3(BH_), dim3(D_), 0, stream, part, ctx);
}

// Round 2
// 284.699 us; speedup vs baseline: 1.4659x; 1.4659x over previous
//
#include <hip/hip_runtime.h>
#include <hip/hip_bf16.h>
#include <math.h>

#define B_   8
#define H_   16
#define BH_  (B_*H_)
#define LK_  4096
#define D_   128

#define SEG   16
#define KSEG  (LK_/SEG)     // 256 keys per score/context block

typedef __attribute__((ext_vector_type(8))) short bf16x8;
typedef __attribute__((ext_vector_type(4))) float f32x4;

// ---------------- fast tanh (f32, ~1e-6 abs err) ----------------
__device__ __forceinline__ float fast_tanh(float x) {
    float ax = fabsf(x);
    float e  = __expf(2.0f * ax);
    float r  = 1.0f - __fdividef(2.0f, e + 1.0f);
    return copysignf(r, x);
}

// f32 -> bf16 hi/lo split (hi = RNE bf16(x), lo = bf16(x - hi))
__device__ __forceinline__ void cvt_hilo(float x, unsigned short& h, unsigned short& l) {
    __hip_bfloat16 bh = __float2bfloat16(x);
    unsigned short hu = __builtin_bit_cast(unsigned short, bh);
    float hf = __uint_as_float((unsigned int)hu << 16);
    __hip_bfloat16 bl = __float2bfloat16(x - hf);
    h = hu;
    l = __builtin_bit_cast(unsigned short, bl);
}

// ---------------- kernel 0: pack W_pre into MFMA B-fragment order (hi/lo) ----
// idx = ((ks*8 + nt)*64 + lane)*8 + j ; k = ks*32 + (lane>>4)*8 + j ; n = nt*16 + (lane&15)
__global__ void pack_kernel(const float* __restrict__ Wpre,
                            unsigned short* __restrict__ Bhi,
                            unsigned short* __restrict__ Blo) {
    int idx  = blockIdx.x * 256 + threadIdx.x;      // 0..16383
    int j    = idx & 7;
    int lane = (idx >> 3) & 63;
    int nt   = (idx >> 9) & 7;
    int ks   = idx >> 12;
    int k    = ks * 32 + (lane >> 4) * 8 + j;
    int n    = nt * 16 + (lane & 15);
    unsigned short h, l;
    cvt_hilo(Wpre[k * D_ + n], h, l);
    Bhi[idx] = h;
    Blo[idx] = l;
}

// ---------------- kernel 1: tq[bh][e] = Q[bh]·W_q[:,e] ----------------
__global__ void tq_kernel(const float* __restrict__ Q,
                          const float* __restrict__ Wq,
                          float* __restrict__ tq) {
    int bh = blockIdx.x;
    int e  = threadIdx.x;
    const float* q = Q + bh * D_;
    float acc = 0.0f;
#pragma unroll 8
    for (int d = 0; d < D_; ++d)
        acc = fmaf(q[d], Wq[d * D_ + e], acc);
    tq[bh * D_ + e] = acc;
}

// ---------------- kernel 2: pre = K@W_pre + b_pre ; energy (MFMA, LDS-free) --
// grid: (LK/128, BH), block 256 = 4 waves; wave owns 32 keys x 128 e.
// A frags loaded straight from global K (each element consumed exactly once),
// converted f32 -> bf16 hi/lo in registers. 3-product split => ~f32 accuracy.
__global__ void __launch_bounds__(256)
main_kernel(const float* __restrict__ K,
            const unsigned short* __restrict__ Bhi,
            const unsigned short* __restrict__ Blo,
            const float* __restrict__ bpre,
            const float* __restrict__ Wv,
            const float* __restrict__ tqg,
            float* __restrict__ pre_out,
            float* __restrict__ energy_out) {
    const int t     = threadIdx.x;
    const int lane  = t & 63;
    const int wv_   = t >> 6;                 // wave 0..3
    const int l15   = lane & 15;
    const int lg    = lane >> 4;
    const int bh    = blockIdx.y;
    const int krow0 = blockIdx.x * 128 + wv_ * 32;

    const float* Ka = K + ((size_t)bh * LK_ + krow0 + l15) * D_ + lg * 8;

    f32x4 acc[2][8];
#pragma unroll
    for (int m = 0; m < 2; ++m)
#pragma unroll
        for (int n = 0; n < 8; ++n)
            acc[m][n] = (f32x4){0.f, 0.f, 0.f, 0.f};

    for (int ks = 0; ks < 4; ++ks) {
        // ---- A fragments: 2 mtiles, hi+lo, direct from global
        bf16x8 ah[2], al[2];
#pragma unroll
        for (int m = 0; m < 2; ++m) {
            const float* p = Ka + (size_t)m * 16 * D_ + ks * 32;
            float4 x0 = *(const float4*)p;
            float4 x1 = *(const float4*)(p + 4);
            float xs[8] = {x0.x, x0.y, x0.z, x0.w, x1.x, x1.y, x1.z, x1.w};
#pragma unroll
            for (int j = 0; j < 8; ++j) {
                unsigned short h, l;
                cvt_hilo(xs[j], h, l);
                ah[m][j] = (short)h;
                al[m][j] = (short)l;
            }
        }
        // ---- B fragments from packed ws (L2-resident), 16B/lane contiguous
        const unsigned short* bhp = Bhi + ((size_t)ks * 4096) + (size_t)lane * 8;
        const unsigned short* blp = Blo + ((size_t)ks * 4096) + (size_t)lane * 8;
#pragma unroll
        for (int n = 0; n < 8; ++n) {
            bf16x8 wh = *(const bf16x8*)(bhp + n * 512);
            bf16x8 wl = *(const bf16x8*)(blp + n * 512);
#pragma unroll
            for (int m = 0; m < 2; ++m) {
                acc[m][n] = __builtin_amdgcn_mfma_f32_16x16x32_bf16(ah[m], wh, acc[m][n], 0, 0, 0);
                acc[m][n] = __builtin_amdgcn_mfma_f32_16x16x32_bf16(ah[m], wl, acc[m][n], 0, 0, 0);
                acc[m][n] = __builtin_amdgcn_mfma_f32_16x16x32_bf16(al[m], wh, acc[m][n], 0, 0, 0);
            }
        }
    }

    // ---- epilogue: +b_pre -> store pre (NT) ; tanh(pre+tq)·W_v -> energy
    float bpv[8], tqv[8], wvv[8];
#pragma unroll
    for (int n = 0; n < 8; ++n) {
        bpv[n] = bpre[n * 16 + l15];
        tqv[n] = tqg[bh * D_ + n * 16 + l15];
        wvv[n] = Wv[n * 16 + l15];
    }

    float ep[2][4];
#pragma unroll
    for (int m = 0; m < 2; ++m)
#pragma unroll
        for (int r = 0; r < 4; ++r)
            ep[m][r] = 0.0f;

#pragma unroll
    for (int m = 0; m < 2; ++m) {
        const int rowb = krow0 + m * 16 + lg * 4;
        float* pb = pre_out + ((size_t)bh * LK_ + rowb) * D_ + l15;
#pragma unroll
        for (int n = 0; n < 8; ++n) {
#pragma unroll
            for (int r = 0; r < 4; ++r) {
                float v = acc[m][n][r] + bpv[n];
                __builtin_nontemporal_store(v, pb + (size_t)r * D_ + n * 16);
                ep[m][r] = fmaf(fast_tanh(v + tqv[n]), wvv[n], ep[m][r]);
            }
        }
    }

    // reduce energy partials across the 16 e-lanes (stays within 16-lane group)
#pragma unroll
    for (int m = 0; m < 2; ++m)
#pragma unroll
        for (int r = 0; r < 4; ++r) {
            float v = ep[m][r];
            v += __shfl_xor(v, 1, 64);
            v += __shfl_xor(v, 2, 64);
            v += __shfl_xor(v, 4, 64);
            v += __shfl_xor(v, 8, 64);
            if (l15 == 0)
                energy_out[(size_t)bh * LK_ + krow0 + m * 16 + lg * 4 + r] = v;
        }
}

// ---------------- kernel 3a: per-(b,h) masked max & sum(exp) ----------------
__global__ void ml_kernel(const float* __restrict__ energy,
                          const int* __restrict__ mask,
                          float* __restrict__ ml) {
    const int bh = blockIdx.x;
    const int t  = threadIdx.x;
    const float* e = energy + (size_t)bh * LK_;
    const int*   m = mask   + (size_t)bh * LK_;

    float mx = -1e30f;
    for (int k = t; k < LK_; k += 256) {
        float v = m[k] ? -1.0e6f : e[k];
        mx = fmaxf(mx, v);
    }
#pragma unroll
    for (int off = 32; off > 0; off >>= 1)
        mx = fmaxf(mx, __shfl_xor(mx, off, 64));
    __shared__ float wmax[4];
    if ((t & 63) == 0) wmax[t >> 6] = mx;
    __syncthreads();
    mx = fmaxf(fmaxf(wmax[0], wmax[1]), fmaxf(wmax[2], wmax[3]));

    float sum = 0.0f;
    for (int k = t; k < LK_; k += 256) {
        float v = m[k] ? -1.0e6f : e[k];
        sum += __expf(v - mx);
    }
#pragma unroll
    for (int off = 32; off > 0; off >>= 1)
        sum += __shfl_xor(sum, off, 64);
    __shared__ float wsum[4];
    if ((t & 63) == 0) wsum[t >> 6] = sum;
    __syncthreads();
    if (t == 0) {
        ml[bh * 2]     = mx;
        ml[bh * 2 + 1] = wsum[0] + wsum[1] + wsum[2] + wsum[3];
    }
}

// ---------------- kernel 3b: score + partial context ----------------
// grid: (SEG, BH), block 256. KSEG=256: one score per thread, float4 V loads.
__global__ void score_ctx_kernel(const float* __restrict__ energy,
                                 const int* __restrict__ mask,
                                 const float* __restrict__ V,
                                 const float* __restrict__ ml,
                                 float* __restrict__ score_out,
                                 float* __restrict__ part) {
    const int seg = blockIdx.x;
    const int bh  = blockIdx.y;
    const int t   = threadIdx.x;
    const int k0  = seg * KSEG;

    __shared__ float sc[KSEG];
    __shared__ float pl[8][136];

    const float mx  = ml[bh * 2];
    const float inv = 1.0f / ml[bh * 2 + 1];

    {
        const size_t gi = (size_t)bh * LK_ + k0 + t;
        float v = mask[gi] ? -1.0e6f : energy[gi];
        float s = __expf(v - mx) * inv;
        sc[t] = s;
        score_out[gi] = s;
    }
    __syncthreads();

    const int d4 = t & 31;           // float4 column
    const int g  = t >> 5;           // k-group 0..7
    const float* Vb = V + ((size_t)bh * LK_ + k0) * D_ + d4 * 4;
    float4 a = make_float4(0.f, 0.f, 0.f, 0.f);
#pragma unroll 4
    for (int kk = g; kk < KSEG; kk += 8) {
        float4 vv = *(const float4*)(Vb + (size_t)kk * D_);
        float s = sc[kk];
        a.x = fmaf(s, vv.x, a.x);
        a.y = fmaf(s, vv.y, a.y);
        a.z = fmaf(s, vv.z, a.z);
        a.w = fmaf(s, vv.w, a.w);
    }
    *(float4*)&pl[g][d4 * 4] = a;
    __syncthreads();

    if (t < 128) {
        float s = 0.0f;
#pragma unroll
        for (int gg = 0; gg < 8; ++gg)
            s += pl[gg][t];
        part[((size_t)bh * SEG + seg) * D_ + t] = s;
    }
}

// ---------------- kernel 3c: combine partial contexts ----------------
__global__ void combine_kernel(const float* __restrict__ part,
                               float* __restrict__ ctx) {
    const int bh = blockIdx.x;
    const int d  = threadIdx.x;
    float s = 0.0f;
#pragma unroll
    for (int g = 0; g < SEG; ++g)
        s += part[((size_t)bh * SEG + g) * D_ + d];
    ctx[bh * D_ + d] = s;
}

// ---------------- launch ----------------
extern "C" void kernel_launch(void* const* d_in, const int* in_sizes, int n_in,
                              void* d_out, int out_size, void* d_ws, size_t ws_size,
                              hipStream_t stream) {
    const float* Q    = (const float*)d_in[0];
    const float* K    = (const float*)d_in[1];
    const float* V    = (const float*)d_in[2];
    const int*   mask = (const int*)  d_in[3];
    // d_in[4] = scale (unused by reference)
    const float* Wpre = (const float*)d_in[5];
    const float* bpre = (const float*)d_in[6];
    const float* Wq   = (const float*)d_in[7];
    const float* Wv   = (const float*)d_in[8];

    float* out   = (float*)d_out;
    float* ctx   = out;                           // [BH][D]
    float* score = out + (size_t)BH_ * D_;        // [BH][LK]
    float* pre   = score + (size_t)BH_ * LK_;     // [BH][LK][D]

    float* w    = (float*)d_ws;
    float* tq   = w;                              // BH*D floats
    float* ml   = tq + (size_t)BH_ * D_;          // BH*2
    float* part = ml + 2 * BH_;                   // BH*SEG*D
    unsigned short* Bhi = (unsigned short*)(part + (size_t)BH_ * SEG * D_); // 16384
    unsigned short* Blo = Bhi + 16384;                                      // 16384

    hipLaunchKernelGGL(pack_kernel, dim3(64), dim3(256), 0, stream, Wpre, Bhi, Blo);
    hipLaunchKernelGGL(tq_kernel, dim3(BH_), dim3(D_), 0, stream, Q, Wq, tq);
    hipLaunchKernelGGL(main_kernel, dim3(LK_ / 128, BH_), dim3(256), 0, stream,
                       K, Bhi, Blo, bpre, Wv, tq, pre, score);
    hipLaunchKernelGGL(ml_kernel, dim3(BH_), dim3(256), 0, stream, score, mask, ml);
    hipLaunchKernelGGL(score_ctx_kernel, dim3(SEG, BH_), dim3(256), 0, stream,
                       score, mask, V, ml, score, part);
    hipLaunchKernelGGL(combine_kernel, dim3(BH_), dim3(D_), 0, stream, part, ctx);
}

// Round 4
// 242.087 us; speedup vs baseline: 1.7239x; 1.1760x over previous
//
#include <hip/hip_runtime.h>
#include <hip/hip_bf16.h>
#include <math.h>

#define B_   8
#define H_   16
#define BH_  (B_*H_)
#define LK_  4096
#define D_   128

#define SEG   16
#define KSEG  (LK_/SEG)     // 256 keys per score/context block

typedef __attribute__((ext_vector_type(8))) short bf16x8;
typedef __attribute__((ext_vector_type(4))) float f32x4;

// ---------------- fast tanh (f32, ~1e-6 abs err) ----------------
__device__ __forceinline__ float fast_tanh(float x) {
    float ax = fabsf(x);
    float e  = __expf(2.0f * ax);
    float r  = 1.0f - __fdividef(2.0f, e + 1.0f);
    return copysignf(r, x);
}

// f32 -> bf16 hi/lo split (hi = RNE bf16(x), lo = bf16(x - hi))
__device__ __forceinline__ void cvt_hilo(float x, unsigned short& h, unsigned short& l) {
    __hip_bfloat16 bh = __float2bfloat16(x);
    unsigned short hu = __builtin_bit_cast(unsigned short, bh);
    float hf = __uint_as_float((unsigned int)hu << 16);
    __hip_bfloat16 bl = __float2bfloat16(x - hf);
    h = hu;
    l = __builtin_bit_cast(unsigned short, bl);
}

__device__ __forceinline__ void cvt8(const float4 a, const float4 b, bf16x8& h, bf16x8& l) {
    float xs[8] = {a.x, a.y, a.z, a.w, b.x, b.y, b.z, b.w};
#pragma unroll
    for (int j = 0; j < 8; ++j) {
        unsigned short hu, lu;
        cvt_hilo(xs[j], hu, lu);
        h[j] = (short)hu;
        l[j] = (short)lu;
    }
}

// ---------------- kernel 0: pack W_pre into MFMA fragment order (hi/lo) ------
// idx = ((ks*8 + nt)*64 + lane)*8 + j ; k = ks*32 + (lane>>4)*8 + j ; n = nt*16 + (lane&15)
// Used as the A-operand (W^T): row=e=(lane&15), k=d — same (lane,j) map.
__global__ void pack_kernel(const float* __restrict__ Wpre,
                            unsigned short* __restrict__ Bhi,
                            unsigned short* __restrict__ Blo) {
    int idx  = blockIdx.x * 256 + threadIdx.x;      // 0..16383
    int j    = idx & 7;
    int lane = (idx >> 3) & 63;
    int nt   = (idx >> 9) & 7;
    int ks   = idx >> 12;
    int k    = ks * 32 + (lane >> 4) * 8 + j;
    int n    = nt * 16 + (lane & 15);
    unsigned short h, l;
    cvt_hilo(Wpre[k * D_ + n], h, l);
    Bhi[idx] = h;
    Blo[idx] = l;
}

// ---------------- kernel 1: tq[bh][e] = Q[bh]·W_q[:,e] ----------------
__global__ void tq_kernel(const float* __restrict__ Q,
                          const float* __restrict__ Wq,
                          float* __restrict__ tq) {
    int bh = blockIdx.x;
    int e  = threadIdx.x;
    const float* q = Q + bh * D_;
    float acc = 0.0f;
#pragma unroll 8
    for (int d = 0; d < D_; ++d)
        acc = fmaf(q[d], Wq[d * D_ + e], acc);
    tq[bh * D_ + e] = acc;
}

// ---------------- kernel 2: pre^T = W^T·K^T (+b) ; energy --------------------
// grid (LK/256, BH), block 256 = 4 waves = (2 key-groups) x (2 e-halves).
// W frags register-resident (128 VGPR/wave); K streamed global->reg with
// one-stage-ahead double-buffered prefetch. 4 iters x 64 keys per block.
__global__ void __launch_bounds__(256, 2)
main_kernel(const float* __restrict__ K,
            const unsigned short* __restrict__ Whi,
            const unsigned short* __restrict__ Wlo,
            const float* __restrict__ bpre,
            const float* __restrict__ Wv,
            const float* __restrict__ tqg,
            float* __restrict__ pre_out,
            float* __restrict__ energy_out) {
    const int t    = threadIdx.x;
    const int lane = t & 63;
    const int wv_  = t >> 6;
    const int kg   = wv_ & 1;            // key group (32 keys within 64-key iter)
    const int eh   = wv_ >> 1;           // e half (64 cols)
    const int l15  = lane & 15;
    const int lg   = lane >> 4;
    const int bh   = blockIdx.y;
    const int kblk = blockIdx.x * 256;

    __shared__ float eLDS[2][2][64];     // [iter parity][eh][key-in-iter]

    // ---- resident W fragments: this wave's e-half, all ks, hi+lo (128 VGPR)
    bf16x8 wfh[4][4], wfl[4][4];
#pragma unroll
    for (int ks = 0; ks < 4; ++ks)
#pragma unroll
        for (int et = 0; et < 4; ++et) {
            size_t idx = (((size_t)ks * 8 + eh * 4 + et) * 64 + lane) * 8;
            wfh[ks][et] = *(const bf16x8*)(Whi + idx);
            wfl[ks][et] = *(const bf16x8*)(Wlo + idx);
        }

    // ---- hoisted epilogue constants (per-wave e-range)
    float4 bpv[4], tqv[4], wvv[4];
#pragma unroll
    for (int et = 0; et < 4; ++et) {
        const int e0 = eh * 64 + et * 16 + lg * 4;
        bpv[et] = *(const float4*)(bpre + e0);
        tqv[et] = *(const float4*)(tqg + bh * D_ + e0);
        wvv[et] = *(const float4*)(Wv + e0);
    }

    // lane's K stream base: row = kblk + kg*32 + kt*16 + l15 ; d-offset lg*8
    const float* Kw = K + ((size_t)bh * LK_ + kblk + kg * 32 + l15) * D_ + lg * 8;

    // ---- prologue: load iter0/ks0 raw K
    float4 rw[2][2][2];                  // [parity][kt][half]
#pragma unroll
    for (int kt = 0; kt < 2; ++kt) {
        rw[0][kt][0] = *(const float4*)(Kw + (size_t)kt * 16 * D_);
        rw[0][kt][1] = *(const float4*)(Kw + (size_t)kt * 16 * D_ + 4);
    }

#pragma unroll
    for (int it = 0; it < 4; ++it) {
        f32x4 acc[2][4];
#pragma unroll
        for (int kt = 0; kt < 2; ++kt)
#pragma unroll
            for (int et = 0; et < 4; ++et)
                acc[kt][et] = (f32x4){0.f, 0.f, 0.f, 0.f};

#pragma unroll
        for (int ks = 0; ks < 4; ++ks) {
            const int cur = ks & 1, nxt = cur ^ 1;
            // issue next-stage loads before consuming current
            if (ks < 3) {
#pragma unroll
                for (int kt = 0; kt < 2; ++kt) {
                    const float* p = Kw + ((size_t)it * 64 + kt * 16) * D_ + (ks + 1) * 32;
                    rw[nxt][kt][0] = *(const float4*)p;
                    rw[nxt][kt][1] = *(const float4*)(p + 4);
                }
            } else if (it < 3) {
#pragma unroll
                for (int kt = 0; kt < 2; ++kt) {
                    const float* p = Kw + ((size_t)(it + 1) * 64 + kt * 16) * D_;
                    rw[nxt][kt][0] = *(const float4*)p;
                    rw[nxt][kt][1] = *(const float4*)(p + 4);
                }
            }
            // convert current raw -> bf16 hi/lo fragments
            bf16x8 kh[2], kl[2];
            cvt8(rw[cur][0][0], rw[cur][0][1], kh[0], kl[0]);
            cvt8(rw[cur][1][0], rw[cur][1][1], kh[1], kl[1]);
            // 24 MFMAs: D[e][key] += Wfrag · Kfrag (3-product hi/lo split)
#pragma unroll
            for (int kt = 0; kt < 2; ++kt)
#pragma unroll
                for (int et = 0; et < 4; ++et) {
                    acc[kt][et] = __builtin_amdgcn_mfma_f32_16x16x32_bf16(wfh[ks][et], kh[kt], acc[kt][et], 0, 0, 0);
                    acc[kt][et] = __builtin_amdgcn_mfma_f32_16x16x32_bf16(wfl[ks][et], kh[kt], acc[kt][et], 0, 0, 0);
                    acc[kt][et] = __builtin_amdgcn_mfma_f32_16x16x32_bf16(wfh[ks][et], kl[kt], acc[kt][et], 0, 0, 0);
                }
        }

        // ---- epilogue: pre store (float4 via f32x4 NT) + energy partial
        const int kb = kblk + it * 64 + kg * 32;
#pragma unroll
        for (int kt = 0; kt < 2; ++kt) {
            float* pb = pre_out + ((size_t)bh * LK_ + kb + kt * 16 + l15) * D_ + eh * 64 + lg * 4;
            float ep = 0.0f;
#pragma unroll
            for (int et = 0; et < 4; ++et) {
                f32x4 a = acc[kt][et];
                f32x4 v;
                v[0] = a[0] + bpv[et].x;
                v[1] = a[1] + bpv[et].y;
                v[2] = a[2] + bpv[et].z;
                v[3] = a[3] + bpv[et].w;
                __builtin_nontemporal_store(v, (f32x4*)(pb + et * 16));
                ep = fmaf(fast_tanh(v[0] + tqv[et].x), wvv[et].x, ep);
                ep = fmaf(fast_tanh(v[1] + tqv[et].y), wvv[et].y, ep);
                ep = fmaf(fast_tanh(v[2] + tqv[et].z), wvv[et].z, ep);
                ep = fmaf(fast_tanh(v[3] + tqv[et].w), wvv[et].w, ep);
            }
            // reduce over the 4 lg groups (e dimension) within the wave
            ep += __shfl_xor(ep, 16, 64);
            ep += __shfl_xor(ep, 32, 64);
            if (lg == 0)
                eLDS[it & 1][eh][kg * 32 + kt * 16 + l15] = ep;
        }
        // lgkmcnt-only barrier: keep prefetched global loads in flight
        asm volatile("s_waitcnt lgkmcnt(0)\n\ts_barrier" ::: "memory");
        if (t < 64) {
            float e = eLDS[it & 1][0][t] + eLDS[it & 1][1][t];
            energy_out[(size_t)bh * LK_ + kblk + it * 64 + t] = e;
        }
    }
}

// ---------------- kernel 3a: per-(b,h) masked max & sum(exp) ----------------
__global__ void ml_kernel(const float* __restrict__ energy,
                          const int* __restrict__ mask,
                          float* __restrict__ ml) {
    const int bh = blockIdx.x;
    const int t  = threadIdx.x;
    const float* e = energy + (size_t)bh * LK_;
    const int*   m = mask   + (size_t)bh * LK_;

    float mx = -1e30f;
    for (int k = t; k < LK_; k += 256) {
        float v = m[k] ? -1.0e6f : e[k];
        mx = fmaxf(mx, v);
    }
#pragma unroll
    for (int off = 32; off > 0; off >>= 1)
        mx = fmaxf(mx, __shfl_xor(mx, off, 64));
    __shared__ float wmax[4];
    if ((t & 63) == 0) wmax[t >> 6] = mx;
    __syncthreads();
    mx = fmaxf(fmaxf(wmax[0], wmax[1]), fmaxf(wmax[2], wmax[3]));

    float sum = 0.0f;
    for (int k = t; k < LK_; k += 256) {
        float v = m[k] ? -1.0e6f : e[k];
        sum += __expf(v - mx);
    }
#pragma unroll
    for (int off = 32; off > 0; off >>= 1)
        sum += __shfl_xor(sum, off, 64);
    __shared__ float wsum[4];
    if ((t & 63) == 0) wsum[t >> 6] = sum;
    __syncthreads();
    if (t == 0) {
        ml[bh * 2]     = mx;
        ml[bh * 2 + 1] = wsum[0] + wsum[1] + wsum[2] + wsum[3];
    }
}

// ---------------- kernel 3b: score + partial context ----------------
// grid: (SEG, BH), block 256. KSEG=256: one score per thread, float4 V loads.
__global__ void score_ctx_kernel(const float* __restrict__ energy,
                                 const int* __restrict__ mask,
                                 const float* __restrict__ V,
                                 const float* __restrict__ ml,
                                 float* __restrict__ score_out,
                                 float* __restrict__ part) {
    const int seg = blockIdx.x;
    const int bh  = blockIdx.y;
    const int t   = threadIdx.x;
    const int k0  = seg * KSEG;

    __shared__ float sc[KSEG];
    __shared__ float pl[8][136];

    const float mx  = ml[bh * 2];
    const float inv = 1.0f / ml[bh * 2 + 1];

    {
        const size_t gi = (size_t)bh * LK_ + k0 + t;
        float v = mask[gi] ? -1.0e6f : energy[gi];
        float s = __expf(v - mx) * inv;
        sc[t] = s;
        score_out[gi] = s;
    }
    __syncthreads();

    const int d4 = t & 31;           // float4 column
    const int g  = t >> 5;           // k-group 0..7
    const float* Vb = V + ((size_t)bh * LK_ + k0) * D_ + d4 * 4;
    float4 a = make_float4(0.f, 0.f, 0.f, 0.f);
#pragma unroll 4
    for (int kk = g; kk < KSEG; kk += 8) {
        float4 vv = *(const float4*)(Vb + (size_t)kk * D_);
        float s = sc[kk];
        a.x = fmaf(s, vv.x, a.x);
        a.y = fmaf(s, vv.y, a.y);
        a.z = fmaf(s, vv.z, a.z);
        a.w = fmaf(s, vv.w, a.w);
    }
    *(float4*)&pl[g][d4 * 4] = a;
    __syncthreads();

    if (t < 128) {
        float s = 0.0f;
#pragma unroll
        for (int gg = 0; gg < 8; ++gg)
            s += pl[gg][t];
        part[((size_t)bh * SEG + seg) * D_ + t] = s;
    }
}

// ---------------- kernel 3c: combine partial contexts ----------------
__global__ void combine_kernel(const float* __restrict__ part,
                               float* __restrict__ ctx) {
    const int bh = blockIdx.x;
    const int d  = threadIdx.x;
    float s = 0.0f;
#pragma unroll
    for (int g = 0; g < SEG; ++g)
        s += part[((size_t)bh * SEG + g) * D_ + d];
    ctx[bh * D_ + d] = s;
}

// ---------------- launch ----------------
extern "C" void kernel_launch(void* const* d_in, const int* in_sizes, int n_in,
                              void* d_out, int out_size, void* d_ws, size_t ws_size,
                              hipStream_t stream) {
    const float* Q    = (const float*)d_in[0];
    const float* K    = (const float*)d_in[1];
    const float* V    = (const float*)d_in[2];
    const int*   mask = (const int*)  d_in[3];
    // d_in[4] = scale (unused by reference)
    const float* Wpre = (const float*)d_in[5];
    const float* bpre = (const float*)d_in[6];
    const float* Wq   = (const float*)d_in[7];
    const float* Wv   = (const float*)d_in[8];

    float* out   = (float*)d_out;
    float* ctx   = out;                           // [BH][D]
    float* score = out + (size_t)BH_ * D_;        // [BH][LK]
    float* pre   = score + (size_t)BH_ * LK_;     // [BH][LK][D]

    float* w    = (float*)d_ws;
    float* tq   = w;                              // BH*D floats
    float* ml   = tq + (size_t)BH_ * D_;          // BH*2
    float* part = ml + 2 * BH_;                   // BH*SEG*D
    unsigned short* Whi = (unsigned short*)(part + (size_t)BH_ * SEG * D_); // 16384
    unsigned short* Wlo = Whi + 16384;                                      // 16384

    hipLaunchKernelGGL(pack_kernel, dim3(64), dim3(256), 0, stream, Wpre, Whi, Wlo);
    hipLaunchKernelGGL(tq_kernel, dim3(BH_), dim3(D_), 0, stream, Q, Wq, tq);
    hipLaunchKernelGGL(main_kernel, dim3(LK_ / 256, BH_), dim3(256), 0, stream,
                       K, Whi, Wlo, bpre, Wv, tq, pre, score);
    hipLaunchKernelGGL(ml_kernel, dim3(BH_), dim3(256), 0, stream, score, mask, ml);
    hipLaunchKernelGGL(score_ctx_kernel, dim3(SEG, BH_), dim3(256), 0, stream,
                       score, mask, V, ml, score, part);
    hipLaunchKernelGGL(combine_kernel, dim3(BH_), dim3(D_), 0, stream, part, ctx);
}